// Round 3
// baseline (456.263 us; speedup 1.0000x reference)
//
#include <hip/hip_runtime.h>
#include <math.h>

// ---------------- problem constants ----------------
#define NPIX 128
#define MASKM 2548
#define NPAD 2560          // padded q count (20*128)
#define MG   6912          // GEMM M = 9 taps * 768
#define KD   768

typedef __attribute__((ext_vector_type(8))) short bf16x8;
typedef __attribute__((ext_vector_type(4))) float f32x4;
typedef __attribute__((ext_vector_type(8))) unsigned short ushort8;

// ---------------- workspace layout ----------------
static constexpr size_t OFF_QI   = 0;
static constexpr size_t OFF_QJ   = OFF_QI + NPAD * 4;
static constexpr size_t OFF_QIDX = OFF_QJ + NPAD * 4;
static constexpr size_t OFF_APIX = OFF_QIDX + 16384 * 4;
static constexpr size_t OFF_PART = OFF_APIX + 16384 * 4;
static constexpr size_t OFF_STAT = OFF_PART + 512 * 8 * 8;
static constexpr size_t OFF_SC   = OFF_STAT + 256;
static constexpr size_t OFF_HM   = OFF_SC + NPAD * 4;
static constexpr size_t OFF_AH   = OFF_HM + (size_t)MASKM * KD * 4;
static constexpr size_t OFF_AL   = OFF_AH + (size_t)MG * KD * 2;
static constexpr size_t OFF_BH   = OFF_AL + (size_t)MG * KD * 2;
static constexpr size_t OFF_BL   = OFF_BH + (size_t)NPAD * KD * 2;
static constexpr size_t OFF_YT   = OFF_BL + (size_t)NPAD * KD * 2;
// X (7.9MB fp32) aliases the head of Yt (70.8MB): dead before k_gemm writes Yt.
static constexpr size_t OFF_X    = OFF_YT;

// ---------------- bf16 hi/lo split helpers ----------------
__device__ __forceinline__ unsigned short f2bf(float f) {
    unsigned u = __float_as_uint(f);
    u = u + 0x7FFFu + ((u >> 16) & 1u);       // RNE
    return (unsigned short)(u >> 16);
}
__device__ __forceinline__ float bf2f(unsigned short h) {
    return __uint_as_float(((unsigned)h) << 16);
}

// ---------------- mask structure (closed form) ----------------
__device__ __forceinline__ bool mask_allowed(int i, int d) {
    if (d == 0) return true;
    if (d <= 15) return true;
    if (d <= 31) return (d >= 17) && ((d & 1) == 1) && ((i & 1) == 0);
    if (d <= 63) return (d >= 35) && ((d & 3) == 3) && ((i & 3) == 0);
    return (d >= 71) && ((d & 7) == 7) && ((i & 7) == 0);
}
__device__ __forceinline__ bool masked_ij(int i, int j) {
    return (j >= i) && mask_allowed(i, j - i);
}

__global__ void k_struct(int* qi, int* qj, int* qidx, int* apix) {
    __shared__ int cnt[NPIX], start[NPIX];
    int i = threadIdx.x;   // 128 threads, one row each
    for (int j = 0; j < NPIX; ++j) qidx[i * NPIX + j] = -1;
    int c = 0;
    for (int d = 0; i + d < NPIX; ++d) if (mask_allowed(i, d)) ++c;
    cnt[i] = c;
    __syncthreads();
    if (i == 0) { int s = 0; for (int r = 0; r < NPIX; ++r) { start[r] = s; s += cnt[r]; } }
    __syncthreads();
    int base = start[i];
    for (int d = 0; i + d < NPIX; ++d)
        if (mask_allowed(i, d)) { qi[base] = i; qj[base] = i + d; qidx[i * NPIX + i + d] = base; ++base; }
    // dilated-mask active flags: pixel (y,x) matters iff any 3x3 neighbor is masked
    int y = i;
    for (int x = 0; x < NPIX; ++x) {
        int act = 0;
        for (int dy = -1; dy <= 1; ++dy)
            for (int dx = -1; dx <= 1; ++dx) {
                int yy = y + dy, xx = x + dx;
                if ((unsigned)yy < 128u && (unsigned)xx < 128u && masked_ij(yy, xx)) act = 1;
            }
        apix[y * NPIX + x] = act;
    }
}

// ---------------- X[c][q] = max(fea[c, i..j]) via sparse table ----------------
__global__ void k_buildX(const float* __restrict__ fea, const int* __restrict__ qi,
                         const int* __restrict__ qj, float* __restrict__ X) {
    __shared__ float tab[8][NPIX];
    int c = blockIdx.x, t = threadIdx.x;
    tab[0][t]      = fea[c * NPIX + t];
    tab[0][t + 64] = fea[c * NPIX + t + 64];
    __syncthreads();
    for (int l = 1; l < 8; ++l) {
        int half = 1 << (l - 1), full = 1 << l;
        for (int i = t; i < NPIX; i += 64)
            if (i + full <= NPIX) tab[l][i] = fmaxf(tab[l - 1][i], tab[l - 1][i + half]);
        __syncthreads();
    }
    for (int q = t; q < NPAD; q += 64) {
        float v = 0.f;
        if (q < MASKM) {
            int i = qi[q], j = qj[q];
            int len = j - i + 1;
            int l = 31 - __clz(len);
            v = fmaxf(tab[l][i], tab[l][j + 1 - (1 << l)]);
        }
        X[c * NPAD + q] = v;
    }
}

// ---------------- fused reorder+split: w1[co][ci*9+tap] -> Ah/Al[(tap*768+co)][ci] ----------------
__global__ __launch_bounds__(256) void k_prepA(const float* __restrict__ w1,
                                               unsigned short* __restrict__ Ah,
                                               unsigned short* __restrict__ Al) {
    __shared__ float tile[64 * 144];   // [co 64][ci16*9tap = 144]
    int co0 = blockIdx.x * 64, ci0 = blockIdx.y * 64;
    int tid = threadIdx.x;
    for (int s = 0; s < 4; ++s) {
        int cib = ci0 + s * 16;
        __syncthreads();   // protect tile from previous iter's readers
        // load 64 rows x 144 floats (contiguous per row), float4, coalesced
        for (int idx = tid; idx < 2304; idx += 256) {
            int row = idx / 36, c4 = idx % 36;
            float4 v = *(const float4*)(w1 + (size_t)(co0 + row) * MG + cib * 9 + c4 * 4);
            *(float4*)&tile[row * 144 + c4 * 4] = v;
        }
        __syncthreads();
        // write: 9 taps x 64 co x 2 halves of 8 ci  (1152 units of 16B)
        for (int idx = tid; idx < 1152; idx += 256) {
            int tap = idx / 128;
            int rem = idx - tap * 128;
            int co = rem >> 1, half = rem & 1;
            ushort8 vh, vl;
            #pragma unroll
            for (int c = 0; c < 8; ++c) {
                float v = tile[co * 144 + (half * 8 + c) * 9 + tap];
                unsigned short hi = f2bf(v);
                vh[c] = hi;
                vl[c] = f2bf(v - bf2f(hi));
            }
            size_t ob = (size_t)(tap * 768 + co0 + co) * KD + cib + half * 8;
            *(ushort8*)(Ah + ob) = vh;
            *(ushort8*)(Al + ob) = vl;
        }
    }
}

// ---------------- transpose + bf16 hi/lo split: src[768][C] -> dst[C][768] ----------------
__global__ void k_trans(const float* __restrict__ src, int C,
                        unsigned short* __restrict__ dh, unsigned short* __restrict__ dl) {
    __shared__ float tile[64][65];
    int c0 = blockIdx.x * 64, k0 = blockIdx.y * 64;
    int t = threadIdx.x;
    int r = t >> 2, cq = (t & 3) << 4;
    const float* s = src + (size_t)(k0 + r) * C + c0 + cq;
    #pragma unroll
    for (int u = 0; u < 16; u += 4) {
        float4 v = *(const float4*)(s + u);
        tile[r][cq + u]     = v.x;
        tile[r][cq + u + 1] = v.y;
        tile[r][cq + u + 2] = v.z;
        tile[r][cq + u + 3] = v.w;
    }
    __syncthreads();
    size_t ob = (size_t)(c0 + r) * KD + k0 + cq;
    #pragma unroll
    for (int u = 0; u < 16; ++u) {
        float v = tile[cq + u][r];
        unsigned short hi = f2bf(v);
        float lo = v - bf2f(hi);
        dh[ob + u] = hi;
        dl[ob + u] = f2bf(lo);
    }
}

// ---------------- bf16x3 MFMA GEMM: Yt[n][m] = sum_k A[m][k] * B[n][k] ----------------
// LDS chunk-XOR swizzle: row r's 16B slot p holds k-chunk (p ^ ((r%16)>>1 & 3)).
// Staging keeps 64B/row global coalescing; ds_read lands on 8 banks x 2-way = conflict-free.
__global__ __launch_bounds__(256, 2) void k_gemm(const unsigned short* __restrict__ Ah,
                                                 const unsigned short* __restrict__ Al,
                                                 const unsigned short* __restrict__ Bh,
                                                 const unsigned short* __restrict__ Bl,
                                                 float* __restrict__ Yt) {
    __shared__ unsigned short sm[4 * 128 * 32];    // Ah|Al|Bh|Bl tiles, 32 KB
    int tid = threadIdx.x;
    int wave = tid >> 6, lane = tid & 63;
    int m0 = blockIdx.y * 128, n0 = blockIdx.x * 128;
    int wm = (wave & 1) << 6, wn = (wave >> 1) << 6;
    int r4 = lane >> 2, c4 = lane & 3;
    int fr = lane & 15, fq = lane >> 4;
    int csw = c4 ^ ((r4 >> 1) & 3);                // staging chunk swizzle
    int fsw = (fq ^ ((fr >> 1) & 3)) * 8;          // fragment slot swizzle (shorts)

    const unsigned short* gsrc[4];
    gsrc[0] = Ah + (size_t)m0 * KD;
    gsrc[1] = Al + (size_t)m0 * KD;
    gsrc[2] = Bh + (size_t)n0 * KD;
    gsrc[3] = Bl + (size_t)n0 * KD;

    f32x4 acc[4][4] = {};

    for (int kb = 0; kb < KD / 32; ++kb) {
        int k0 = kb * 32;
        __syncthreads();
        #pragma unroll
        for (int mat = 0; mat < 4; ++mat) {
            #pragma unroll
            for (int h2 = 0; h2 < 2; ++h2) {
                int rg = wave * 2 + h2;            // 16-row group 0..7
                const unsigned short* g = gsrc[mat] + (size_t)(rg * 16 + r4) * KD + k0 + csw * 8;
                unsigned short* l = &sm[mat * 4096 + rg * 512];
                __builtin_amdgcn_global_load_lds(
                    (const __attribute__((address_space(1))) unsigned int*)g,
                    (__attribute__((address_space(3))) unsigned int*)l, 16, 0, 0);
            }
        }
        __syncthreads();
        bf16x8 ah[4], al[4], bh[4], bl[4];
        #pragma unroll
        for (int i = 0; i < 4; ++i) {
            ah[i] = *(const bf16x8*)&sm[0 * 4096 + (wm + i * 16 + fr) * 32 + fsw];
            al[i] = *(const bf16x8*)&sm[1 * 4096 + (wm + i * 16 + fr) * 32 + fsw];
            bh[i] = *(const bf16x8*)&sm[2 * 4096 + (wn + i * 16 + fr) * 32 + fsw];
            bl[i] = *(const bf16x8*)&sm[3 * 4096 + (wn + i * 16 + fr) * 32 + fsw];
        }
        #pragma unroll
        for (int mi = 0; mi < 4; ++mi)
            #pragma unroll
            for (int ni = 0; ni < 4; ++ni) {
                acc[mi][ni] = __builtin_amdgcn_mfma_f32_16x16x32_bf16(ah[mi], bh[ni], acc[mi][ni], 0, 0, 0);
                acc[mi][ni] = __builtin_amdgcn_mfma_f32_16x16x32_bf16(ah[mi], bl[ni], acc[mi][ni], 0, 0, 0);
                acc[mi][ni] = __builtin_amdgcn_mfma_f32_16x16x32_bf16(al[mi], bh[ni], acc[mi][ni], 0, 0, 0);
            }
    }
    #pragma unroll
    for (int mi = 0; mi < 4; ++mi)
        #pragma unroll
        for (int ni = 0; ni < 4; ++ni) {
            int n = n0 + wn + ni * 16 + fr;
            int m = m0 + wm + mi * 16 + fq * 4;
            *(f32x4*)(Yt + (size_t)n * MG + m) = acc[mi][ni];
        }
}

// ---------------- gather taps -> hm (masked rows) + GN partial sums (active pixels only) ----------------
__global__ __launch_bounds__(256) void k_gather(const float* __restrict__ Yt,
                                                const int* __restrict__ qidx,
                                                const int* __restrict__ apix,
                                                float* __restrict__ hm,
                                                double* __restrict__ part) {
    __shared__ double red1[256 * 4], red2[256 * 4];
    int tid = threadIdx.x;
    int wave = tid >> 6, lane = tid & 63;
    double a1[3] = {0, 0, 0}, a2[3] = {0, 0, 0};
    int gs[3];
    #pragma unroll
    for (int s = 0; s < 3; ++s) gs[s] = (64 * s + lane) / 48;

    for (int it = 0; it < 8; ++it) {
        int p = blockIdx.x * 32 + wave * 8 + it;   // wave-uniform pixel
        if (!apix[p]) continue;                    // h==0 here: no stats, no write
        int y = p >> 7, x = p & 127;
        float4 hv[3] = {};
        #pragma unroll
        for (int tap = 0; tap < 9; ++tap) {
            int i = y + tap / 3 - 1, j = x + tap % 3 - 1;
            if ((unsigned)i < 128u && (unsigned)j < 128u) {
                int q = qidx[i * NPIX + j];
                if (q >= 0) {
                    const float* yr = Yt + (size_t)q * MG + tap * 768 + lane * 4;
                    #pragma unroll
                    for (int s = 0; s < 3; ++s) {
                        float4 v = *(const float4*)(yr + s * 256);
                        hv[s].x += v.x; hv[s].y += v.y; hv[s].z += v.z; hv[s].w += v.w;
                    }
                }
            }
        }
        int qp = qidx[p];
        if (qp >= 0) {
            #pragma unroll
            for (int s = 0; s < 3; ++s)
                *(float4*)(hm + (size_t)qp * KD + s * 256 + lane * 4) = hv[s];
        }
        #pragma unroll
        for (int s = 0; s < 3; ++s) {
            a1[s] += (double)hv[s].x + (double)hv[s].y + (double)hv[s].z + (double)hv[s].w;
            a2[s] += (double)hv[s].x * hv[s].x + (double)hv[s].y * hv[s].y +
                     (double)hv[s].z * hv[s].z + (double)hv[s].w * hv[s].w;
        }
    }
    #pragma unroll
    for (int g = 0; g < 4; ++g) { red1[tid * 4 + g] = 0.0; red2[tid * 4 + g] = 0.0; }
    #pragma unroll
    for (int s = 0; s < 3; ++s) { red1[tid * 4 + gs[s]] = a1[s]; red2[tid * 4 + gs[s]] = a2[s]; }
    __syncthreads();
    if (tid < 4) {
        double s1 = 0.0, s2 = 0.0;
        for (int i = 0; i < 256; ++i) { s1 += red1[i * 4 + tid]; s2 += red2[i * 4 + tid]; }
        part[blockIdx.x * 8 + tid] = s1;
        part[blockIdx.x * 8 + 4 + tid] = s2;
    }
}

__global__ void k_finalize(const double* __restrict__ part, float* __restrict__ stats) {
    int g = threadIdx.x;
    if (g >= 4) return;
    double s1 = 0.0, s2 = 0.0;
    for (int b = 0; b < 512; ++b) { s1 += part[b * 8 + g]; s2 += part[b * 8 + 4 + g]; }
    double cnt = 192.0 * 16384.0;
    double mean = s1 / cnt;
    double var = s2 / cnt - mean * mean;
    stats[g] = (float)mean;
    stats[4 + g] = (float)(1.0 / sqrt(var + 1e-5));
}

// ---------------- fused GN + ReLU + 1x1 conv + sigmoid at mask positions ----------------
__global__ void k_score(const float* __restrict__ hm, const float* __restrict__ stats,
                        const float* __restrict__ gamma, const float* __restrict__ beta,
                        const float* __restrict__ w2, const float* __restrict__ b2,
                        float* __restrict__ scores) {
    int q = blockIdx.x * 4 + (threadIdx.x >> 6);
    int lane = threadIdx.x & 63;
    if (q >= MASKM) return;
    const float* hp = hm + (size_t)q * KD;
    float s = 0.f;
    for (int c = lane; c < KD; c += 64) {
        int g = c / 192;
        float v = (hp[c] - stats[g]) * stats[4 + g] * gamma[c] + beta[c];
        s += fmaxf(v, 0.f) * w2[c];
    }
    for (int o = 32; o; o >>= 1) s += __shfl_down(s, o, 64);
    if (lane == 0) scores[q] = 1.f / (1.f + expf(-(s + b2[0])));
}

// ---------------- greedy NMS via 5-round iterative argmax (== stable sorted greedy) ----------------
__device__ __forceinline__ unsigned long long shfl_down_u64(unsigned long long v, int o) {
    unsigned lo = (unsigned)v, hi = (unsigned)(v >> 32);
    lo = __shfl_down(lo, o, 64);
    hi = __shfl_down(hi, o, 64);
    return ((unsigned long long)hi << 32) | lo;
}

__global__ void k_nms(const float* __restrict__ scores, const int* __restrict__ qi,
                      const int* __restrict__ qj, const int* __restrict__ durp,
                      float* __restrict__ out) {
    __shared__ unsigned long long key[MASKM];
    __shared__ float ss[MASKM], ee[MASKM];
    __shared__ unsigned char st[MASKM];     // 0 free, 1 suppressed, 2 kept, 3 picked-fallback
    __shared__ unsigned long long wm0[16], wm1[16];
    __shared__ int sh_pick, sh_keeper, keepq[5];
    __shared__ float sh_s0, sh_e0;
    int t = threadIdx.x;                    // 1024
    float delta = (float)(*durp) / 128.f;
    for (int i = t; i < MASKM; i += 1024) {
        unsigned sb = __float_as_uint(scores[i]);            // scores > 0: bits monotonic
        key[i] = ((unsigned long long)sb << 32) | (unsigned)(4095 - i);  // tie: lower q wins
        ss[i] = qi[i] * delta;
        ee[i] = (qj[i] + 1) * delta;
        st[i] = 0;
    }
    __syncthreads();
    for (int round = 0; round < 5; ++round) {
        unsigned long long b0 = 0, b1 = 0;
        for (int i = t; i < MASKM; i += 1024) {
            unsigned char s = st[i];
            unsigned long long k = key[i];
            if (s == 0) { if (k > b0) b0 = k; }
            else if (s == 1) { if (k > b1) b1 = k; }
        }
        for (int o = 32; o; o >>= 1) {
            unsigned long long u0 = shfl_down_u64(b0, o), u1 = shfl_down_u64(b1, o);
            if (u0 > b0) b0 = u0;
            if (u1 > b1) b1 = u1;
        }
        if ((t & 63) == 0) { wm0[t >> 6] = b0; wm1[t >> 6] = b1; }
        __syncthreads();
        if (t == 0) {
            unsigned long long B0 = 0, B1 = 0;
            for (int w = 0; w < 16; ++w) {
                if (wm0[w] > B0) B0 = wm0[w];
                if (wm1[w] > B1) B1 = wm1[w];
            }
            int keeper = (B0 != 0);
            unsigned long long B = keeper ? B0 : B1;
            int q = 4095 - (int)(B & 0xFFFFFFFFull);
            st[q] = keeper ? 2 : 3;
            sh_pick = q; sh_keeper = keeper;
            sh_s0 = ss[q]; sh_e0 = ee[q];
            keepq[round] = q;
        }
        __syncthreads();
        if (sh_keeper) {
            float s0 = sh_s0, e0 = sh_e0;
            for (int i = t; i < MASKM; i += 1024) {
                if (st[i] == 0) {
                    float inter = fminf(ee[i], e0) - fmaxf(ss[i], s0);
                    if (inter > 0.f) {
                        float uni = fmaxf(ee[i], e0) - fminf(ss[i], s0);
                        if (inter / uni > 0.5f) st[i] = 1;
                    }
                }
            }
        }
        __syncthreads();
    }
    if (t < 5) { out[t * 2] = ss[keepq[t]]; out[t * 2 + 1] = ee[keepq[t]]; }
}

// ---------------- launch ----------------
extern "C" void kernel_launch(void* const* d_in, const int* in_sizes, int n_in,
                              void* d_out, int out_size, void* d_ws, size_t ws_size,
                              hipStream_t stream) {
    const float* fea   = (const float*)d_in[0];
    const int*   dur   = (const int*)d_in[1];
    const float* w1    = (const float*)d_in[2];
    const float* gamma = (const float*)d_in[3];
    const float* beta  = (const float*)d_in[4];
    const float* w2    = (const float*)d_in[5];
    const float* b2    = (const float*)d_in[6];
    float* out = (float*)d_out;

    char* ws = (char*)d_ws;
    int*    qi     = (int*)(ws + OFF_QI);
    int*    qj     = (int*)(ws + OFF_QJ);
    int*    qidx   = (int*)(ws + OFF_QIDX);
    int*    apix   = (int*)(ws + OFF_APIX);
    double* part   = (double*)(ws + OFF_PART);
    float*  stats  = (float*)(ws + OFF_STAT);
    float*  scores = (float*)(ws + OFF_SC);
    float*  hm     = (float*)(ws + OFF_HM);
    unsigned short* AhU = (unsigned short*)(ws + OFF_AH);
    unsigned short* AlU = (unsigned short*)(ws + OFF_AL);
    unsigned short* BhU = (unsigned short*)(ws + OFF_BH);
    unsigned short* BlU = (unsigned short*)(ws + OFF_BL);
    float*  Yt     = (float*)(ws + OFF_YT);
    float*  X      = (float*)(ws + OFF_X);   // aliases Yt head

    k_struct<<<1, 128, 0, stream>>>(qi, qj, qidx, apix);
    k_buildX<<<768, 64, 0, stream>>>(fea, qi, qj, X);
    k_prepA<<<dim3(12, 12), 256, 0, stream>>>(w1, AhU, AlU);
    k_trans<<<dim3(40, 12), 256, 0, stream>>>(X, NPAD, BhU, BlU);
    k_gemm<<<dim3(20, 54), 256, 0, stream>>>(AhU, AlU, BhU, BlU, Yt);
    k_gather<<<512, 256, 0, stream>>>(Yt, qidx, apix, hm, part);
    k_finalize<<<1, 64, 0, stream>>>(part, stats);
    k_score<<<637, 256, 0, stream>>>(hm, stats, gamma, beta, w2, b2, scores);
    k_nms<<<1, 1024, 0, stream>>>(scores, qi, qj, dur, out);
}

// Round 4
// 319.015 us; speedup vs baseline: 1.4302x; 1.4302x over previous
//
#include <hip/hip_runtime.h>
#include <math.h>

// ---------------- problem constants ----------------
#define NPIX 128
#define MASKM 2548
#define NPAD 2560          // padded q count (20*128)
#define MG   6912          // GEMM M = 9 taps * 768
#define KD   768

typedef __attribute__((ext_vector_type(8))) short bf16x8;
typedef __attribute__((ext_vector_type(4))) float f32x4;
typedef __attribute__((ext_vector_type(8))) unsigned short ushort8;

// ---------------- workspace layout ----------------
static constexpr size_t OFF_QI   = 0;
static constexpr size_t OFF_QJ   = OFF_QI + NPAD * 4;
static constexpr size_t OFF_QIDX = OFF_QJ + NPAD * 4;
static constexpr size_t OFF_APIX = OFF_QIDX + 16384 * 4;
static constexpr size_t OFF_START= OFF_APIX + 16384 * 4;
static constexpr size_t OFF_PART = OFF_START + 128 * 4;
static constexpr size_t OFF_STAT = OFF_PART + 512 * 8 * 8;
static constexpr size_t OFF_SC   = OFF_STAT + 256;
static constexpr size_t OFF_HM   = OFF_SC + NPAD * 4;
static constexpr size_t OFF_AH   = OFF_HM + (size_t)MASKM * KD * 4;
static constexpr size_t OFF_AL   = OFF_AH + (size_t)MG * KD * 2;
static constexpr size_t OFF_BH   = OFF_AL + (size_t)MG * KD * 2;
static constexpr size_t OFF_BL   = OFF_BH + (size_t)NPAD * KD * 2;
static constexpr size_t OFF_YT   = OFF_BL + (size_t)NPAD * KD * 2;
// X (7.9MB fp32) aliases the head of Yt (70.8MB): dead before k_gemm writes Yt.
static constexpr size_t OFF_X    = OFF_YT;

// ---------------- bf16 hi/lo split helpers ----------------
__device__ __forceinline__ unsigned short f2bf(float f) {
    unsigned u = __float_as_uint(f);
    u = u + 0x7FFFu + ((u >> 16) & 1u);       // RNE
    return (unsigned short)(u >> 16);
}
__device__ __forceinline__ float bf2f(unsigned short h) {
    return __uint_as_float(((unsigned)h) << 16);
}

// ---------------- mask structure (closed form) ----------------
__device__ __forceinline__ bool mask_allowed(int i, int d) {
    if (d == 0) return true;
    if (d <= 15) return true;
    if (d <= 31) return (d >= 17) && ((d & 1) == 1) && ((i & 1) == 0);
    if (d <= 63) return (d >= 35) && ((d & 3) == 3) && ((i & 3) == 0);
    return (d >= 71) && ((d & 7) == 7) && ((i & 7) == 0);
}
__device__ __forceinline__ bool masked_ij(int i, int j) {
    return (j >= i) && (j < NPIX) && (i >= 0) && mask_allowed(i, j - i);
}

// 1 block x 128: per-row q-offsets only (cheap)
__global__ void k_rowstart(int* startv) {
    __shared__ int cnt[NPIX];
    int i = threadIdx.x;
    int c = 0;
    for (int d = 0; i + d < NPIX; ++d) if (mask_allowed(i, d)) ++c;
    cnt[i] = c;
    __syncthreads();
    if (i == 0) {
        int s = 0;
        for (int r = 0; r < NPIX; ++r) { startv[r] = s; s += cnt[r]; }
    }
}

// 64 blocks x 256: one thread per pixel -> qidx, apix, qi/qj
__global__ void k_fill(const int* __restrict__ startv, int* __restrict__ qi,
                       int* __restrict__ qj, int* __restrict__ qidx,
                       int* __restrict__ apix) {
    int p = blockIdx.x * 256 + threadIdx.x;
    int i = p >> 7, j = p & 127;
    int q = -1;
    if (masked_ij(i, j)) {
        int d = j - i, r = 0;
        for (int dd = 0; dd < d; ++dd) r += mask_allowed(i, dd) ? 1 : 0;
        q = startv[i] + r;
        qi[q] = i; qj[q] = j;
    }
    qidx[p] = q;
    int act = 0;
    #pragma unroll
    for (int dy = -1; dy <= 1; ++dy)
        #pragma unroll
        for (int dx = -1; dx <= 1; ++dx)
            if (masked_ij(i + dy, j + dx)) act = 1;
    apix[p] = act;
}

// ---------------- X[c][q] = max(fea[c, i..j]) via sparse table ----------------
__global__ void k_buildX(const float* __restrict__ fea, const int* __restrict__ qi,
                         const int* __restrict__ qj, float* __restrict__ X) {
    __shared__ float tab[8][NPIX];
    int c = blockIdx.x, t = threadIdx.x;
    tab[0][t]      = fea[c * NPIX + t];
    tab[0][t + 64] = fea[c * NPIX + t + 64];
    __syncthreads();
    for (int l = 1; l < 8; ++l) {
        int half = 1 << (l - 1), full = 1 << l;
        for (int i = t; i < NPIX; i += 64)
            if (i + full <= NPIX) tab[l][i] = fmaxf(tab[l - 1][i], tab[l - 1][i + half]);
        __syncthreads();
    }
    for (int q = t; q < NPAD; q += 64) {
        float v = 0.f;
        if (q < MASKM) {
            int i = qi[q], j = qj[q];
            int len = j - i + 1;
            int l = 31 - __clz(len);
            v = fmaxf(tab[l][i], tab[l][j + 1 - (1 << l)]);
        }
        X[c * NPAD + q] = v;
    }
}

// ---------------- fused reorder+split: w1[co][ci*9+tap] -> Ah/Al[(tap*768+co)][ci] ----------------
__global__ __launch_bounds__(256) void k_prepA(const float* __restrict__ w1,
                                               unsigned short* __restrict__ Ah,
                                               unsigned short* __restrict__ Al) {
    __shared__ float tile[64 * 144];   // [co 64][ci16*9tap = 144]
    int co0 = blockIdx.x * 64, ci0 = blockIdx.y * 64;
    int tid = threadIdx.x;
    for (int s = 0; s < 4; ++s) {
        int cib = ci0 + s * 16;
        __syncthreads();
        for (int idx = tid; idx < 2304; idx += 256) {
            int row = idx / 36, c4 = idx % 36;
            float4 v = *(const float4*)(w1 + (size_t)(co0 + row) * MG + cib * 9 + c4 * 4);
            *(float4*)&tile[row * 144 + c4 * 4] = v;
        }
        __syncthreads();
        for (int idx = tid; idx < 1152; idx += 256) {
            int tap = idx / 128;
            int rem = idx - tap * 128;
            int co = rem >> 1, half = rem & 1;
            ushort8 vh, vl;
            #pragma unroll
            for (int c = 0; c < 8; ++c) {
                float v = tile[co * 144 + (half * 8 + c) * 9 + tap];
                unsigned short hi = f2bf(v);
                vh[c] = hi;
                vl[c] = f2bf(v - bf2f(hi));
            }
            size_t ob = (size_t)(tap * 768 + co0 + co) * KD + cib + half * 8;
            *(ushort8*)(Ah + ob) = vh;
            *(ushort8*)(Al + ob) = vl;
        }
    }
}

// ---------------- transpose + bf16 hi/lo split: src[768][C] -> dst[C][768] ----------------
__global__ void k_trans(const float* __restrict__ src, int C,
                        unsigned short* __restrict__ dh, unsigned short* __restrict__ dl) {
    __shared__ float tile[64][65];
    int c0 = blockIdx.x * 64, k0 = blockIdx.y * 64;
    int t = threadIdx.x;
    int r = t >> 2, cq = (t & 3) << 4;
    const float* s = src + (size_t)(k0 + r) * C + c0 + cq;
    #pragma unroll
    for (int u = 0; u < 16; u += 4) {
        float4 v = *(const float4*)(s + u);
        tile[r][cq + u]     = v.x;
        tile[r][cq + u + 1] = v.y;
        tile[r][cq + u + 2] = v.z;
        tile[r][cq + u + 3] = v.w;
    }
    __syncthreads();
    size_t ob = (size_t)(c0 + r) * KD + k0 + cq;
    #pragma unroll
    for (int u = 0; u < 16; ++u) {
        float v = tile[cq + u][r];
        unsigned short hi = f2bf(v);
        float lo = v - bf2f(hi);
        dh[ob + u] = hi;
        dl[ob + u] = f2bf(lo);
    }
}

// ---------------- bf16x3 MFMA GEMM: Yt[n][m] = sum_k A[m][k] * B[n][k] ----------------
// LDS chunk-XOR swizzle keeps 64B/row coalescing; ds_read 8 banks x 2-way = conflict-free.
__global__ __launch_bounds__(256, 2) void k_gemm(const unsigned short* __restrict__ Ah,
                                                 const unsigned short* __restrict__ Al,
                                                 const unsigned short* __restrict__ Bh,
                                                 const unsigned short* __restrict__ Bl,
                                                 float* __restrict__ Yt) {
    __shared__ unsigned short sm[4 * 128 * 32];    // Ah|Al|Bh|Bl tiles, 32 KB
    int tid = threadIdx.x;
    int wave = tid >> 6, lane = tid & 63;
    int m0 = blockIdx.y * 128, n0 = blockIdx.x * 128;
    int wm = (wave & 1) << 6, wn = (wave >> 1) << 6;
    int r4 = lane >> 2, c4 = lane & 3;
    int fr = lane & 15, fq = lane >> 4;
    int csw = c4 ^ ((r4 >> 1) & 3);                // staging chunk swizzle
    int fsw = (fq ^ ((fr >> 1) & 3)) * 8;          // fragment slot swizzle (shorts)

    const unsigned short* gsrc[4];
    gsrc[0] = Ah + (size_t)m0 * KD;
    gsrc[1] = Al + (size_t)m0 * KD;
    gsrc[2] = Bh + (size_t)n0 * KD;
    gsrc[3] = Bl + (size_t)n0 * KD;

    f32x4 acc[4][4] = {};

    for (int kb = 0; kb < KD / 32; ++kb) {
        int k0 = kb * 32;
        __syncthreads();
        #pragma unroll
        for (int mat = 0; mat < 4; ++mat) {
            #pragma unroll
            for (int h2 = 0; h2 < 2; ++h2) {
                int rg = wave * 2 + h2;            // 16-row group 0..7
                const unsigned short* g = gsrc[mat] + (size_t)(rg * 16 + r4) * KD + k0 + csw * 8;
                unsigned short* l = &sm[mat * 4096 + rg * 512];
                __builtin_amdgcn_global_load_lds(
                    (const __attribute__((address_space(1))) unsigned int*)g,
                    (__attribute__((address_space(3))) unsigned int*)l, 16, 0, 0);
            }
        }
        __syncthreads();
        bf16x8 ah[4], al[4], bh[4], bl[4];
        #pragma unroll
        for (int i = 0; i < 4; ++i) {
            ah[i] = *(const bf16x8*)&sm[0 * 4096 + (wm + i * 16 + fr) * 32 + fsw];
            al[i] = *(const bf16x8*)&sm[1 * 4096 + (wm + i * 16 + fr) * 32 + fsw];
            bh[i] = *(const bf16x8*)&sm[2 * 4096 + (wn + i * 16 + fr) * 32 + fsw];
            bl[i] = *(const bf16x8*)&sm[3 * 4096 + (wn + i * 16 + fr) * 32 + fsw];
        }
        #pragma unroll
        for (int mi = 0; mi < 4; ++mi)
            #pragma unroll
            for (int ni = 0; ni < 4; ++ni) {
                acc[mi][ni] = __builtin_amdgcn_mfma_f32_16x16x32_bf16(ah[mi], bh[ni], acc[mi][ni], 0, 0, 0);
                acc[mi][ni] = __builtin_amdgcn_mfma_f32_16x16x32_bf16(ah[mi], bl[ni], acc[mi][ni], 0, 0, 0);
                acc[mi][ni] = __builtin_amdgcn_mfma_f32_16x16x32_bf16(al[mi], bh[ni], acc[mi][ni], 0, 0, 0);
            }
    }
    #pragma unroll
    for (int mi = 0; mi < 4; ++mi)
        #pragma unroll
        for (int ni = 0; ni < 4; ++ni) {
            int n = n0 + wn + ni * 16 + fr;
            int m = m0 + wm + mi * 16 + fq * 4;
            *(f32x4*)(Yt + (size_t)n * MG + m) = acc[mi][ni];
        }
}

// ---------------- gather taps -> hm (masked rows) + GN partial sums (active pixels only) ----------------
__global__ __launch_bounds__(256) void k_gather(const float* __restrict__ Yt,
                                                const int* __restrict__ qidx,
                                                const int* __restrict__ apix,
                                                float* __restrict__ hm,
                                                double* __restrict__ part) {
    __shared__ double red1[256 * 4], red2[256 * 4];
    int tid = threadIdx.x;
    int wave = tid >> 6, lane = tid & 63;
    double a1[3] = {0, 0, 0}, a2[3] = {0, 0, 0};
    int gs[3];
    #pragma unroll
    for (int s = 0; s < 3; ++s) gs[s] = (64 * s + lane) / 48;

    for (int it = 0; it < 8; ++it) {
        int p = blockIdx.x * 32 + wave * 8 + it;   // wave-uniform pixel
        if (!apix[p]) continue;
        int y = p >> 7, x = p & 127;
        float4 hv[3] = {};
        #pragma unroll
        for (int tap = 0; tap < 9; ++tap) {
            int i = y + tap / 3 - 1, j = x + tap % 3 - 1;
            if ((unsigned)i < 128u && (unsigned)j < 128u) {
                int q = qidx[i * NPIX + j];
                if (q >= 0) {
                    const float* yr = Yt + (size_t)q * MG + tap * 768 + lane * 4;
                    #pragma unroll
                    for (int s = 0; s < 3; ++s) {
                        float4 v = *(const float4*)(yr + s * 256);
                        hv[s].x += v.x; hv[s].y += v.y; hv[s].z += v.z; hv[s].w += v.w;
                    }
                }
            }
        }
        int qp = qidx[p];
        if (qp >= 0) {
            #pragma unroll
            for (int s = 0; s < 3; ++s)
                *(float4*)(hm + (size_t)qp * KD + s * 256 + lane * 4) = hv[s];
        }
        #pragma unroll
        for (int s = 0; s < 3; ++s) {
            a1[s] += (double)hv[s].x + (double)hv[s].y + (double)hv[s].z + (double)hv[s].w;
            a2[s] += (double)hv[s].x * hv[s].x + (double)hv[s].y * hv[s].y +
                     (double)hv[s].z * hv[s].z + (double)hv[s].w * hv[s].w;
        }
    }
    #pragma unroll
    for (int g = 0; g < 4; ++g) { red1[tid * 4 + g] = 0.0; red2[tid * 4 + g] = 0.0; }
    #pragma unroll
    for (int s = 0; s < 3; ++s) { red1[tid * 4 + gs[s]] = a1[s]; red2[tid * 4 + gs[s]] = a2[s]; }
    __syncthreads();
    if (tid < 4) {
        double s1 = 0.0, s2 = 0.0;
        for (int i = 0; i < 256; ++i) { s1 += red1[i * 4 + tid]; s2 += red2[i * 4 + tid]; }
        part[blockIdx.x * 8 + tid] = s1;
        part[blockIdx.x * 8 + 4 + tid] = s2;
    }
}

__global__ void k_finalize(const double* __restrict__ part, float* __restrict__ stats) {
    int g = threadIdx.x;
    if (g >= 4) return;
    double s1 = 0.0, s2 = 0.0;
    for (int b = 0; b < 512; ++b) { s1 += part[b * 8 + g]; s2 += part[b * 8 + 4 + g]; }
    double cnt = 192.0 * 16384.0;
    double mean = s1 / cnt;
    double var = s2 / cnt - mean * mean;
    stats[g] = (float)mean;
    stats[4 + g] = (float)(1.0 / sqrt(var + 1e-5));
}

// ---------------- fused GN + ReLU + 1x1 conv + sigmoid at mask positions ----------------
__global__ void k_score(const float* __restrict__ hm, const float* __restrict__ stats,
                        const float* __restrict__ gamma, const float* __restrict__ beta,
                        const float* __restrict__ w2, const float* __restrict__ b2,
                        float* __restrict__ scores) {
    int q = blockIdx.x * 4 + (threadIdx.x >> 6);
    int lane = threadIdx.x & 63;
    if (q >= MASKM) return;
    const float* hp = hm + (size_t)q * KD;
    float s = 0.f;
    for (int c = lane; c < KD; c += 64) {
        int g = c / 192;
        float v = (hp[c] - stats[g]) * stats[4 + g] * gamma[c] + beta[c];
        s += fmaxf(v, 0.f) * w2[c];
    }
    for (int o = 32; o; o >>= 1) s += __shfl_down(s, o, 64);
    if (lane == 0) scores[q] = 1.f / (1.f + expf(-(s + b2[0])));
}

// ---------------- greedy NMS via 5-round iterative argmax (== stable sorted greedy) ----------------
__device__ __forceinline__ unsigned long long shfl_down_u64(unsigned long long v, int o) {
    unsigned lo = (unsigned)v, hi = (unsigned)(v >> 32);
    lo = __shfl_down(lo, o, 64);
    hi = __shfl_down(hi, o, 64);
    return ((unsigned long long)hi << 32) | lo;
}

__global__ void k_nms(const float* __restrict__ scores, const int* __restrict__ qi,
                      const int* __restrict__ qj, const int* __restrict__ durp,
                      float* __restrict__ out) {
    __shared__ unsigned long long key[MASKM];
    __shared__ float ss[MASKM], ee[MASKM];
    __shared__ unsigned char st[MASKM];     // 0 free, 1 suppressed, 2 kept, 3 picked-fallback
    __shared__ unsigned long long wm0[16], wm1[16];
    __shared__ int sh_keeper, keepq[5];
    __shared__ float sh_s0, sh_e0;
    int t = threadIdx.x;                    // 1024
    float delta = (float)(*durp) / 128.f;
    for (int i = t; i < MASKM; i += 1024) {
        unsigned sb = __float_as_uint(scores[i]);            // scores > 0: bits monotonic
        key[i] = ((unsigned long long)sb << 32) | (unsigned)(4095 - i);  // tie: lower q wins
        ss[i] = qi[i] * delta;
        ee[i] = (qj[i] + 1) * delta;
        st[i] = 0;
    }
    __syncthreads();
    for (int round = 0; round < 5; ++round) {
        unsigned long long b0 = 0, b1 = 0;
        for (int i = t; i < MASKM; i += 1024) {
            unsigned char s = st[i];
            unsigned long long k = key[i];
            if (s == 0) { if (k > b0) b0 = k; }
            else if (s == 1) { if (k > b1) b1 = k; }
        }
        for (int o = 32; o; o >>= 1) {
            unsigned long long u0 = shfl_down_u64(b0, o), u1 = shfl_down_u64(b1, o);
            if (u0 > b0) b0 = u0;
            if (u1 > b1) b1 = u1;
        }
        if ((t & 63) == 0) { wm0[t >> 6] = b0; wm1[t >> 6] = b1; }
        __syncthreads();
        if (t == 0) {
            unsigned long long B0 = 0, B1 = 0;
            for (int w = 0; w < 16; ++w) {
                if (wm0[w] > B0) B0 = wm0[w];
                if (wm1[w] > B1) B1 = wm1[w];
            }
            int keeper = (B0 != 0);
            unsigned long long B = keeper ? B0 : B1;
            int q = 4095 - (int)(B & 0xFFFFFFFFull);
            st[q] = keeper ? 2 : 3;
            sh_keeper = keeper;
            sh_s0 = ss[q]; sh_e0 = ee[q];
            keepq[round] = q;
        }
        __syncthreads();
        if (sh_keeper) {
            float s0 = sh_s0, e0 = sh_e0;
            for (int i = t; i < MASKM; i += 1024) {
                if (st[i] == 0) {
                    float inter = fminf(ee[i], e0) - fmaxf(ss[i], s0);
                    if (inter > 0.f) {
                        float uni = fmaxf(ee[i], e0) - fminf(ss[i], s0);
                        if (inter / uni > 0.5f) st[i] = 1;
                    }
                }
            }
        }
        __syncthreads();
    }
    if (t < 5) { out[t * 2] = ss[keepq[t]]; out[t * 2 + 1] = ee[keepq[t]]; }
}

// ---------------- launch ----------------
extern "C" void kernel_launch(void* const* d_in, const int* in_sizes, int n_in,
                              void* d_out, int out_size, void* d_ws, size_t ws_size,
                              hipStream_t stream) {
    const float* fea   = (const float*)d_in[0];
    const int*   dur   = (const int*)d_in[1];
    const float* w1    = (const float*)d_in[2];
    const float* gamma = (const float*)d_in[3];
    const float* beta  = (const float*)d_in[4];
    const float* w2    = (const float*)d_in[5];
    const float* b2    = (const float*)d_in[6];
    float* out = (float*)d_out;

    char* ws = (char*)d_ws;
    int*    qi     = (int*)(ws + OFF_QI);
    int*    qj     = (int*)(ws + OFF_QJ);
    int*    qidx   = (int*)(ws + OFF_QIDX);
    int*    apix   = (int*)(ws + OFF_APIX);
    int*    startv = (int*)(ws + OFF_START);
    double* part   = (double*)(ws + OFF_PART);
    float*  stats  = (float*)(ws + OFF_STAT);
    float*  scores = (float*)(ws + OFF_SC);
    float*  hm     = (float*)(ws + OFF_HM);
    unsigned short* AhU = (unsigned short*)(ws + OFF_AH);
    unsigned short* AlU = (unsigned short*)(ws + OFF_AL);
    unsigned short* BhU = (unsigned short*)(ws + OFF_BH);
    unsigned short* BlU = (unsigned short*)(ws + OFF_BL);
    float*  Yt     = (float*)(ws + OFF_YT);
    float*  X      = (float*)(ws + OFF_X);   // aliases Yt head

    k_rowstart<<<1, 128, 0, stream>>>(startv);
    k_fill<<<64, 256, 0, stream>>>(startv, qi, qj, qidx, apix);
    k_buildX<<<768, 64, 0, stream>>>(fea, qi, qj, X);
    k_prepA<<<dim3(12, 12), 256, 0, stream>>>(w1, AhU, AlU);
    k_trans<<<dim3(40, 12), 256, 0, stream>>>(X, NPAD, BhU, BlU);
    k_gemm<<<dim3(20, 54), 256, 0, stream>>>(AhU, AlU, BhU, BlU, Yt);
    k_gather<<<512, 256, 0, stream>>>(Yt, qidx, apix, hm, part);
    k_finalize<<<1, 64, 0, stream>>>(part, stats);
    k_score<<<637, 256, 0, stream>>>(hm, stats, gamma, beta, w2, b2, scores);
    k_nms<<<1, 1024, 0, stream>>>(scores, qi, qj, dur, out);
}